// Round 4
// baseline (309.029 us; speedup 1.0000x reference)
//
#include <hip/hip_runtime.h>
#include <cstdint>
#include <cstddef>

#define HID 128
#define SEQL 28
#define INP 28
#define NL 10
#define NC 10
#define BATCH 4096
#define BB 16             // batch rows per block
#define STRD 136          // padded row stride in halfs (272 B, b128-aligned)
#define BUFH (16 * STRD)  // halfs per 16x128 activation sub-buffer
#define NPAIRS 14         // 28 timesteps as 14 pairs

typedef _Float16 half8 __attribute__((ext_vector_type(8)));
typedef _Float16 half4 __attribute__((ext_vector_type(4)));
typedef float    f32x4 __attribute__((ext_vector_type(4)));

// ---------------- ws layout (bytes) ----------------
// Wcat : [NL][HID][256] f16 : 655360 @ 0   row n: [Wih(128, l0 zero-padded) | Whh(128)]
// bias : [NL][HID] f32      : 5120   @ 655360   (b_ih + b_hh)
// seq  : [BATCH][SEQL][HID] f16 : 29360128 @ 660480 (group-boundary acts; L3 then L7)
#define WS_WCAT_OFF 0
#define WS_BIAS_OFF 655360
#define WS_SEQ_OFF  660480

__global__ void convert_weights(const float* __restrict__ Wih0,
                                const float* __restrict__ Wih,
                                const float* __restrict__ Whh,
                                const float* __restrict__ bih,
                                const float* __restrict__ bhh,
                                _Float16* __restrict__ Wcat,
                                float* __restrict__ bias) {
  int tg = blockIdx.x * blockDim.x + threadIdx.x;
  if (tg >= NL * HID * 16) return;
  int r = tg >> 4, seg = tg & 15;
  int l = r / HID, n = r % HID;
  int k0 = seg * 16;
  _Float16* dst = Wcat + (size_t)r * 256 + k0;
  if (l == 0) {
#pragma unroll
    for (int i = 0; i < 16; ++i) {
      int k = k0 + i;
      float v = 0.f;
      if (k < INP) v = Wih0[n * INP + k];
      else if (k >= HID) v = Whh[(size_t)n * HID + (k - HID)];
      dst[i] = (_Float16)v;
    }
  } else {
    const float* src = (k0 < HID)
        ? (Wih + ((size_t)(l - 1) * HID + n) * HID + k0)
        : (Whh + ((size_t)l * HID + n) * HID + (k0 - HID));
#pragma unroll
    for (int i = 0; i < 16; ++i) dst[i] = (_Float16)src[i];
  }
  if (seg == 0) bias[r] = bih[r] + bhh[r];
}

__device__ __forceinline__ float tanh_fast(float v) {
  float e = __expf(2.f * v);
  return 1.f - 2.f / (e + 1.f);
}

// Light barrier: order LDS only; global loads/stores stay in flight.
__device__ __forceinline__ void barrier_light() {
  __builtin_amdgcn_sched_barrier(0);
  asm volatile("s_waitcnt lgkmcnt(0)" ::: "memory");
  __builtin_amdgcn_s_barrier();
  __builtin_amdgcn_sched_barrier(0);
}

// Same-wave LDS write->read fence (step A h-write -> step B H-read).
__device__ __forceinline__ void lds_fence() {
  __builtin_amdgcn_sched_barrier(0);
  asm volatile("s_waitcnt lgkmcnt(0)" ::: "memory");
  __builtin_amdgcn_sched_barrier(0);
}

// 256 threads = 4 waves; wave s = layer-slot s owning ALL 128 n-cols of layer
// L = g*4+s (groups {0-3},{4-7},{8-9}). Weights 64 half8 = 256 regs/wave
// (AGPR-resident, direct MFMA A-operand). Each tick computes TWO timesteps:
// pair P = tau - s, t = 2P, 2P+1. Step B's H-operand is the wave's OWN step-A
// output: same-wave LDS write -> lgkmcnt(0) -> read, NO barrier. 49 ticks
// total vs 91 in round 3, and no 2-wave A-tile read duplication.
// LDS pair-buffers (2*BUFH halfs = sub0|sub1): O[s][p] = idx s*2+p (s=0..2),
// O3 = idx 6 (single: only self-read). Slot s tick tau (pb=P&1):
//   IN: s==0 ? global prefetch regs : O[s-1][pb] (sub0=t even, sub1=t odd)
//   H(step A): O[s][1-pb].sub1 (self, last tick)   H(step B): O[s][pb].sub0
//   writes O[s][pb] sub0/sub1 (+ seq for s==3, g<2)
// Group boundary __syncthreads orders seq RAW (g's slot3 -> g+1's slot0).
__global__ __launch_bounds__(256, 1) void rnn_fused(
    const float* __restrict__ x,
    const _Float16* __restrict__ Wcat,
    const float* __restrict__ bias,
    const float* __restrict__ fcW,
    const float* __restrict__ fcb,
    _Float16* __restrict__ seq,
    float* __restrict__ out) {
  __shared__ _Float16 lds[BUFH * 14] __attribute__((aligned(16)));

  const int tid    = threadIdx.x;
  const int lane15 = tid & 15;        // batch row m (MFMA D col)
  const int quad   = (tid >> 4) & 3;  // MFMA quad
  const int s      = tid >> 6;        // wave id = layer slot 0..3
  const int b0     = blockIdx.x * BB;

  const int rdoff = lane15 * STRD + quad * 8;  // B-frag read base (+ks*32)
  const int wroff = lane15 * STRD + quad * 4;  // D write base (+nn*16)

  half8 wf[8][8];    // weights [n-subtile][k-frag] (ks 0-3 = IN, 4-7 = H)
  f32x4 bias4[8];

  for (int g = 0; g < 3; ++g) {
    const int L = g * 4 + s;  // >= NL -> idle slot (barriers only)
    if (L < NL) {
      const _Float16* Wl = Wcat + (size_t)L * HID * 256;
#pragma unroll
      for (int nn = 0; nn < 8; ++nn) {
#pragma unroll
        for (int ks = 0; ks < 8; ++ks)
          wf[nn][ks] = *(const half8*)(Wl + (size_t)(nn * 16 + lane15) * 256 + ks * 32 + quad * 8);
        bias4[nn] = *(const f32x4*)(bias + L * HID + nn * 16 + quad * 4);
      }
    }
    // FULL barrier: prev group's LDS reads done before re-zeroing; per-wave
    // vmcnt drain orders prev group's seq stores before this group's loads.
    __syncthreads();
    {
      uint4 z; z.x = z.y = z.z = z.w = 0u;
      for (int i = tid; i < (BUFH * 14) / 8; i += 256) ((uint4*)lds)[i] = z;
    }

    // slot-0 input prefetch (1 pair = 2 timesteps ahead, single bank:
    // reissued only after step-B MFMAs consumed the old values)
    f32x4 pfx4[4];  // g0: 2 steps x 8 f32 of x
    half8 pfs[8];   // g>=1: 2 steps x 4 B-frags straight from seq

    auto prefetch = [&](int P1) {
      if (g == 0) {
#pragma unroll
        for (int st = 0; st < 2; ++st) {
          const float* xb = x + ((size_t)(b0 + lane15) * SEQL + (2 * P1 + st)) * INP + quad * 8;
          pfx4[st * 2] = *(const f32x4*)xb;
          if (quad < 3) pfx4[st * 2 + 1] = *(const f32x4*)(xb + 4);
          else { f32x4 z4 = {0.f, 0.f, 0.f, 0.f}; pfx4[st * 2 + 1] = z4; }
        }
      } else {
#pragma unroll
        for (int st = 0; st < 2; ++st)
#pragma unroll
          for (int k = 0; k < 4; ++k)
            pfs[st * 4 + k] = *(const half8*)(seq + ((size_t)(b0 + lane15) * SEQL + (2 * P1 + st)) * HID + k * 32 + quad * 8);
      }
    };
    auto mkfragx = [&](int st) -> half8 {  // g0 slot0: f32 x -> f16 B-frag
      half8 r;
#pragma unroll
      for (int i = 0; i < 4; ++i) r[i] = (_Float16)pfx4[st * 2][i];
#pragma unroll
      for (int i = 0; i < 4; ++i) r[4 + i] = (_Float16)pfx4[st * 2 + 1][i];
      return r;
    };

    // one RNN step: acc = bias + IN*Wih + H*Whh; h = tanh; write LDS (+seq)
    auto do_step = [&](const half8 (&infr)[4], int nki, const _Float16* Hb,
                       _Float16* Ob, int t, bool wseq, bool do_pf, int P1) {
      half8 ha[4];
#pragma unroll
      for (int k = 0; k < 4; ++k) ha[k] = *(const half8*)(Hb + rdoff + k * 32);
      f32x4 acc[8];
#pragma unroll
      for (int nn = 0; nn < 8; ++nn) acc[nn] = bias4[nn];
      if (nki == 1) {
#pragma unroll
        for (int nn = 0; nn < 8; ++nn)
          acc[nn] = __builtin_amdgcn_mfma_f32_16x16x32_f16(wf[nn][0], infr[0], acc[nn], 0, 0, 0);
      } else {
#pragma unroll
        for (int ks = 0; ks < 4; ++ks)
#pragma unroll
          for (int nn = 0; nn < 8; ++nn)
            acc[nn] = __builtin_amdgcn_mfma_f32_16x16x32_f16(wf[nn][ks], infr[ks], acc[nn], 0, 0, 0);
      }
#pragma unroll
      for (int ks = 0; ks < 4; ++ks)
#pragma unroll
        for (int nn = 0; nn < 8; ++nn)
          acc[nn] = __builtin_amdgcn_mfma_f32_16x16x32_f16(wf[nn][4 + ks], ha[ks], acc[nn], 0, 0, 0);
      if (do_pf) prefetch(P1);  // after MFMAs consumed old pf regs (WAR-safe)
#pragma unroll
      for (int nn = 0; nn < 8; ++nn) {
        half4 o;
#pragma unroll
        for (int r = 0; r < 4; ++r) o[r] = (_Float16)tanh_fast(acc[nn][r]);
        *(half4*)(Ob + wroff + nn * 16) = o;
        if (wseq)
          *(half4*)(seq + ((size_t)(b0 + lane15) * SEQL + t) * HID + nn * 16 + quad * 4) = o;
      }
    };

    if (s == 0) prefetch(0);

    const int Tg = (g == 2) ? 15 : 17;
    for (int tau = 0; tau < Tg; ++tau) {
      barrier_light();
      const int P = tau - s;
      if (L < NL && (unsigned)P < (unsigned)NPAIRS) {
        const int pb = P & 1;
        _Float16* OwA;       // this pair's write buffer (sub0 = t even)
        const _Float16* HbA; // step-A H source: prev pair's sub1
        if (s == 3) { OwA = lds + 6 * 2 * BUFH; HbA = OwA + BUFH; }
        else {
          OwA = lds + (s * 2 + pb) * 2 * BUFH;
          HbA = lds + (s * 2 + (1 - pb)) * 2 * BUFH + BUFH;
        }
        half8 ia[4], ib[4];
        if (s == 0) {
          if (g == 0) { ia[0] = mkfragx(0); ib[0] = mkfragx(1); }
          else {
#pragma unroll
            for (int k = 0; k < 4; ++k) { ia[k] = pfs[k]; ib[k] = pfs[4 + k]; }
          }
        } else {
          const _Float16* INa = lds + ((s - 1) * 2 + pb) * 2 * BUFH;
#pragma unroll
          for (int k = 0; k < 4; ++k) ia[k] = *(const half8*)(INa + rdoff + k * 32);
#pragma unroll
          for (int k = 0; k < 4; ++k) ib[k] = *(const half8*)(INa + BUFH + rdoff + k * 32);
        }
        const int nki  = (g == 0 && s == 0) ? 1 : 4;
        const bool wsq = (s == 3) && (g < 2);
        // step A: t = 2P
        do_step(ia, nki, HbA, OwA, 2 * P, wsq, false, 0);
        lds_fence();  // step-A h-write complete before step-B H-read
        // step B: t = 2P+1, H = sub0 just written by self
        do_step(ib, nki, OwA, OwA + BUFH, 2 * P + 1, wsq,
                (s == 0) && (P + 1 < NPAIRS), P + 1);
      }
    }
  }
  __syncthreads();

  // --- FC on layer-9 h at t=27: g2 slot1 pair13 step B -> buffer idx 3 sub1 ---
  if (tid < BB * NC) {
    int c = tid >> 4;
    int b = tid & 15;
    float acc = fcb[c];
    const float* wr = fcW + c * HID;
    const _Float16* hr = lds + 7 * BUFH + b * STRD;
#pragma unroll
    for (int k0 = 0; k0 < HID; k0 += 8) {
      half8 h = *(const half8*)(hr + k0);
      f32x4 w0 = *(const f32x4*)(wr + k0);
      f32x4 w1 = *(const f32x4*)(wr + k0 + 4);
#pragma unroll
      for (int j = 0; j < 4; ++j)
        acc += (float)h[j] * w0[j] + (float)h[j + 4] * w1[j];
    }
    out[(size_t)(b0 + b) * NC + c] = acc;
  }
}

extern "C" void kernel_launch(void* const* d_in, const int* in_sizes, int n_in,
                              void* d_out, int out_size, void* d_ws, size_t ws_size,
                              hipStream_t stream) {
  const float* x    = (const float*)d_in[0];
  const float* Wih0 = (const float*)d_in[1];
  const float* Wih  = (const float*)d_in[2];
  const float* Whh  = (const float*)d_in[3];
  const float* bih  = (const float*)d_in[4];
  const float* bhh  = (const float*)d_in[5];
  const float* fcW  = (const float*)d_in[6];
  const float* fcb  = (const float*)d_in[7];
  float* out = (float*)d_out;

  _Float16* Wcat = (_Float16*)((char*)d_ws + WS_WCAT_OFF);
  float*    bs   = (float*)((char*)d_ws + WS_BIAS_OFF);
  _Float16* seq  = (_Float16*)((char*)d_ws + WS_SEQ_OFF);

  convert_weights<<<dim3(80), dim3(256), 0, stream>>>(Wih0, Wih, Whh, bih, bhh, Wcat, bs);
  rnn_fused<<<dim3(BATCH / BB), dim3(256), 0, stream>>>(x, Wcat, bs, fcW, fcb, seq, out);
}